// Round 14
// baseline (5096.612 us; speedup 1.0000x reference)
//
#include <hip/hip_runtime.h>
#include <math.h>

#define KNN_EPS 1e-8f
// Spatial grid: domain [0,256)^3, cell h=16 -> 16^3 = 4096 cells.
#define GH 16.0f
#define GC 16
#define NCELLS (GC * GC * GC)
#define MARGIN 1.0f   // >> max |noisy_d - true_d| (~0.05) -> safe pruning
#define CAP 384       // staged candidates per block; 27-cell mean 132
#define CAPR 64       // ref bucket slots/cell (mean 4.9; spill fallback)
#define CAPQ 96       // query bucket slots/cell (mean 39; spill fallback)

// ---------------------------------------------------------------------------
// Validated arithmetic (round 8, absmax 0.0547):
//   rsq/qsq: non-fused sequential squares; t: asc FMA chain;
//   d = max(fma(-2,t,fl(qsq+rsq)), 0); epilogue: +eps, IEEE div, seq sums.
// Selection: (d, idx) lexicographic min-3 -- order-independent, bit-identical
// across r10-r13 restructures (so atomic bucket order is harmless).
// DO NOT change roundings -- only execution structure.
// ---------------------------------------------------------------------------

__device__ __forceinline__ int cell_coord(float v) {
    int c = (int)floorf(v * (1.0f / GH));
    return min(max(c, 0), GC - 1);
}

// Single pass: scatter refs AND packed queries into per-cell buckets.
// Overflow (astronomically rare, Poisson tails) goes to spill lists that the
// consumers always check -> correctness never depends on the capacities.
__global__ void fused_scatter_kernel(
    const float* __restrict__ xyz1, int n1,
    const float* __restrict__ xyz2,
    const float* __restrict__ motion, int n2, int C,
    int* __restrict__ counts, int* __restrict__ qcounts,
    float4* __restrict__ rbuck, float4* __restrict__ qbuck,
    float4* __restrict__ refspill, int* __restrict__ rsn,
    float4* __restrict__ qspill, int* __restrict__ qsn)
{
#pragma clang fp contract(off)
    int i = blockIdx.x * blockDim.x + threadIdx.x;
    if (i < n1) {
        float x = xyz1[3 * i + 0];
        float y = xyz1[3 * i + 1];
        float z = xyz1[3 * i + 2];
        int cid = (cell_coord(z) * GC + cell_coord(y)) * GC + cell_coord(x);
        int pos = atomicAdd(&counts[cid], 1);
        float4 v = make_float4(x, y, z, __int_as_float(i));
        if (pos < CAPR) rbuck[cid * CAPR + pos] = v;
        else { int sp = atomicAdd(rsn, 1); refspill[sp] = v; }
    }
    int nq = n2 * C;
    if (i < nq) {
        int n = i / C;
        float qx = xyz2[3 * n + 0] + motion[3 * i + 0];   // validated adds
        float qy = xyz2[3 * n + 1] + motion[3 * i + 1];
        float qz = xyz2[3 * n + 2] + motion[3 * i + 2];
        int cid = (cell_coord(qz) * GC + cell_coord(qy)) * GC + cell_coord(qx);
        int pos = atomicAdd(&qcounts[cid], 1);
        float4 v = make_float4(qx, qy, qz, __int_as_float(i));
        if (pos < CAPQ) qbuck[cid * CAPQ + pos] = v;
        else { int sp = atomicAdd(qsn, 1); qspill[sp] = v; }
    }
}

// (d, idx)-lexicographic insert: order-independent == validated stable scan.
__device__ __forceinline__ void top3_insert_lex(float d, int j,
                                                float& bd0, float& bd1, float& bd2,
                                                int& bi0, int& bi1, int& bi2) {
    if (d < bd2 || (d == bd2 && j < bi2)) {
        if (d < bd1 || (d == bd1 && j < bi1)) {
            bd2 = bd1; bi2 = bi1;
            if (d < bd0 || (d == bd0 && j < bi0)) {
                bd1 = bd0; bi1 = bi0;
                bd0 = d;   bi0 = j;
            } else {
                bd1 = d;   bi1 = j;
            }
        } else {
            bd2 = d;       bi2 = j;
        }
    }
}

// Validated candidate evaluation (round 8 roundings, rsq recomputed bit-equal)
__device__ __forceinline__ void eval_candidate(
    float4 r, float qx, float qy, float qz, float qsq,
    float& bd0, float& bd1, float& bd2, int& bi0, int& bi1, int& bi2) {
    int ridx = __float_as_int(r.w);
    float rsq = r.x * r.x + r.y * r.y;
    rsq = rsq + r.z * r.z;
    float t = fmaf(qz, r.z, fmaf(qy, r.y, qx * r.x));
    float h = qsq + rsq;
    float d = fmaxf(fmaf(-2.0f, t, h), 0.0f);
    top3_insert_lex(d, ridx, bd0, bd1, bd2, bi0, bi1, bi2);
}

// Rigorous certification radius after scanning cell-rings <= rho.
__device__ __forceinline__ float cert_radius(float qx, float qy, float qz,
                                             int icx, int icy, int icz, int rho) {
    float R = INFINITY;
    if (icx - rho > 0)      R = fminf(R, qx - (float)(icx - rho) * GH);
    if (icx + rho < GC - 1) R = fminf(R, (float)(icx + rho + 1) * GH - qx);
    if (icy - rho > 0)      R = fminf(R, qy - (float)(icy - rho) * GH);
    if (icy + rho < GC - 1) R = fminf(R, (float)(icy + rho + 1) * GH - qy);
    if (icz - rho > 0)      R = fminf(R, qz - (float)(icz - rho) * GH);
    if (icz + rho < GC - 1) R = fminf(R, (float)(icz + rho + 1) * GH - qz);
    return R;
}

// Validated epilogue (round 8) -> writes out[qid]
__device__ __forceinline__ void epilogue_store(
    float bd0, float bd1, float bd2, int bi0, int bi1, int bi2,
    int qid, int C, const float* __restrict__ point1, float* __restrict__ out) {
#pragma clang fp contract(off)
    float dd0 = bd0 + KNN_EPS;
    float dd1 = bd1 + KNN_EPS;
    float dd2 = bd2 + KNN_EPS;
    float w0 = 1.0f / dd0;
    float w1 = 1.0f / dd1;
    float w2 = 1.0f / dd2;
    float s  = w0 + w1;
    s = s + w2;
    float m = fmaxf(s, 3.0f);
    w0 = w0 / m;
    w1 = w1 / m;
    w2 = w2 / m;
    const int c = qid - (qid / C) * C;
    float p0 = point1[bi0 * C + c];
    float p1 = point1[bi1 * C + c];
    float p2 = point1[bi2 * C + c];
    float acc = w0 * p0 + w1 * p1;
    acc = acc + w2 * p2;
    out[qid] = acc;
}

// One block (2 waves) per cell. Descriptors loaded by 27 PARALLEL lanes
// (r13's serial lane-0 walk of 18 dependent L2 loads was the per-block fixed
// cost dominating the kernel). Staging via per-thread binary search over the
// 27-entry LDS prefix. Waves split the candidate list; wave1's partial top-3
// merges through LDS (order-independent -> bit-exact).
__global__ __launch_bounds__(128, 8) void knn_cell_kernel(
    const float4* __restrict__ rbuck,
    const int*   __restrict__ counts,
    const float4* __restrict__ refspill,
    const int*   __restrict__ rsn,
    const float4* __restrict__ qbuck,
    const int*   __restrict__ qcounts,
    const float* __restrict__ point1,
    float* __restrict__ out,
    int C)
{
#pragma clang fp contract(off)
    const int cell = blockIdx.x;
    const int qn = min(qcounts[cell], CAPQ);
    if (qn == 0) return;
    const int qbase = cell * CAPQ;

    const int tid = threadIdx.x;
    const int lane = tid & 63;
    const int wave = tid >> 6;

    const int icx = cell & (GC - 1);
    const int icy = (cell >> 4) & (GC - 1);
    const int icz = cell >> 8;

    __shared__ float4 cand[CAP];
    __shared__ int rcid[27], rlen[27], rofs[27], rst[27];
    __shared__ int total_s, ovf_s, rsn_s;
    __shared__ float pbd[64][3];
    __shared__ int   pbi[64][3];

    if (tid < 27) {
        int dz = tid / 9 - 1, dy = (tid / 3) % 3 - 1, dx = tid % 3 - 1;
        int cz = icz + dz, cy = icy + dy, cx = icx + dx;
        int ok = (cz >= 0 && cz < GC && cy >= 0 && cy < GC && cx >= 0 && cx < GC);
        int cid = ok ? (cz * GC + cy) * GC + cx : 0;
        rcid[tid] = cid;
        rlen[tid] = ok ? min(counts[cid], CAPR) : 0;
    }
    if (tid == 32) rsn_s = *rsn;
    __syncthreads();
    if (tid == 0) {   // pure-VALU 27-element prefix on LDS-resident ints
        int run = 0, ovf = 0;
        for (int r = 0; r < 27; ++r) {
            int len = rlen[r];
            int st = min(len, CAP - run);
            rofs[r] = run; rst[r] = st;
            run += st;
            if (st < len) ovf = 1;
        }
        total_s = run; ovf_s = ovf;
    }
    __syncthreads();

    const int total = total_s;
    const int ovf = ovf_s;
    const int rspn = rsn_s;

    // stage: thread t copies items t, t+128, ... ; segment found by binary
    // search for the LAST seg with rofs <= i (correct across zero-len segs).
    for (int i = tid; i < total; i += 128) {
        int lo = 0, hi = 26;
        while (lo < hi) {
            int mid = (lo + hi + 1) >> 1;
            if (rofs[mid] <= i) lo = mid; else hi = mid - 1;
        }
        cand[i] = rbuck[rcid[lo] * CAPR + (i - rofs[lo])];
    }
    __syncthreads();

    const int half = total >> 1;
    const int k0 = wave ? half : 0;
    const int k1 = wave ? total : half;

    const int niter = (qn + 63) >> 6;
    for (int it = 0; it < niter; ++it) {
        const int qo = it * 64 + lane;
        const bool active = qo < qn;
        float4 Q = qbuck[qbase + (active ? qo : 0)];
        const float qx = Q.x, qy = Q.y, qz = Q.z;
        const int qid = __float_as_int(Q.w);
        float qsq = qx * qx + qy * qy;
        qsq = qsq + qz * qz;

        float bd0 = INFINITY, bd1 = INFINITY, bd2 = INFINITY;
        int   bi0 = 0,        bi1 = 0,        bi2 = 0;

        int k = k0;
        for (; k + 4 <= k1; k += 4) {
            float4 c0 = cand[k + 0];
            float4 c1 = cand[k + 1];
            float4 c2 = cand[k + 2];
            float4 c3 = cand[k + 3];
            eval_candidate(c0, qx, qy, qz, qsq, bd0, bd1, bd2, bi0, bi1, bi2);
            eval_candidate(c1, qx, qy, qz, qsq, bd0, bd1, bd2, bi0, bi1, bi2);
            eval_candidate(c2, qx, qy, qz, qsq, bd0, bd1, bd2, bi0, bi1, bi2);
            eval_candidate(c3, qx, qy, qz, qsq, bd0, bd1, bd2, bi0, bi1, bi2);
        }
        for (; k < k1; ++k)
            eval_candidate(cand[k], qx, qy, qz, qsq, bd0, bd1, bd2, bi0, bi1, bi2);

        if (wave == 1) {
            pbd[lane][0] = bd0; pbd[lane][1] = bd1; pbd[lane][2] = bd2;
            pbi[lane][0] = bi0; pbi[lane][1] = bi1; pbi[lane][2] = bi2;
        }
        __syncthreads();

        if (wave == 0) {
            for (int m = 0; m < 3; ++m) {
                float d = pbd[lane][m];
                if (d < INFINITY)
                    top3_insert_lex(d, pbi[lane][m], bd0, bd1, bd2, bi0, bi1, bi2);
            }
            // spilled refs (normally zero-trip)
            for (int k2 = 0; k2 < rspn; ++k2)
                eval_candidate(refspill[k2], qx, qy, qz, qsq,
                               bd0, bd1, bd2, bi0, bi1, bi2);
            // LDS overflow remainder (normally zero-trip)
            if (ovf) {
                for (int r = 0; r < 27; ++r)
                    for (int kk = rst[r]; kk < rlen[r]; ++kk)
                        eval_candidate(rbuck[rcid[r] * CAPR + kk], qx, qy, qz, qsq,
                                       bd0, bd1, bd2, bi0, bi1, bi2);
            }
            // rigorous ring-1 certification; rare escalation to rings >= 2
            float R = cert_radius(qx, qy, qz, icx, icy, icz, 1);
            if (!(bd2 + MARGIN <= R * R)) {
                for (int rho = 2; rho < GC; ++rho) {
                    for (int dz = -rho; dz <= rho; ++dz) {
                        int cz = icz + dz;
                        if (cz < 0 || cz >= GC) continue;
                        int adz = (dz < 0) ? -dz : dz;
                        for (int dy = -rho; dy <= rho; ++dy) {
                            int cy = icy + dy;
                            if (cy < 0 || cy >= GC) continue;
                            int ady = (dy < 0) ? -dy : dy;
                            int step = (adz == rho || ady == rho) ? 1 : 2 * rho;
                            for (int dx = -rho; dx <= rho; dx += step) {
                                int cx = icx + dx;
                                if (cx < 0 || cx >= GC) continue;
                                int cid = (cz * GC + cy) * GC + cx;
                                int e = min(counts[cid], CAPR);
                                for (int s = 0; s < e; ++s)
                                    eval_candidate(rbuck[cid * CAPR + s],
                                                   qx, qy, qz, qsq,
                                                   bd0, bd1, bd2, bi0, bi1, bi2);
                            }
                        }
                    }
                    float Rr = cert_radius(qx, qy, qz, icx, icy, icz, rho);
                    if (bd2 + MARGIN <= Rr * Rr) break;  // Rr=INF also breaks
                }
            }

            if (active)
                epilogue_store(bd0, bd1, bd2, bi0, bi1, bi2, qid, C, point1, out);
        }
        if (it + 1 < niter) __syncthreads();  // protect pbd/pbi reuse
    }
}

// Spilled queries (normally zero): exhaustive scan over all buckets + ref
// spill -- exact, order-independent selection -> bit-identical result.
__global__ __launch_bounds__(64) void qspill_kernel(
    const float4* __restrict__ qspill, const int* __restrict__ qsn,
    const float4* __restrict__ rbuck, const int* __restrict__ counts,
    const float4* __restrict__ refspill, const int* __restrict__ rsn,
    const float* __restrict__ point1, float* __restrict__ out, int C)
{
#pragma clang fp contract(off)
    const int nsp = *qsn;
    const int rspn = *rsn;
    for (int s = threadIdx.x; s < nsp; s += 64) {
        float4 Q = qspill[s];
        const float qx = Q.x, qy = Q.y, qz = Q.z;
        const int qid = __float_as_int(Q.w);
        float qsq = qx * qx + qy * qy;
        qsq = qsq + qz * qz;
        float bd0 = INFINITY, bd1 = INFINITY, bd2 = INFINITY;
        int   bi0 = 0,        bi1 = 0,        bi2 = 0;
        for (int cid = 0; cid < NCELLS; ++cid) {
            int e = min(counts[cid], CAPR);
            for (int k = 0; k < e; ++k)
                eval_candidate(rbuck[cid * CAPR + k], qx, qy, qz, qsq,
                               bd0, bd1, bd2, bi0, bi1, bi2);
        }
        for (int k = 0; k < rspn; ++k)
            eval_candidate(refspill[k], qx, qy, qz, qsq,
                           bd0, bd1, bd2, bi0, bi1, bi2);
        epilogue_store(bd0, bd1, bd2, bi0, bi1, bi2, qid, C, point1, out);
    }
}

extern "C" void kernel_launch(void* const* d_in, const int* in_sizes, int n_in,
                              void* d_out, int out_size, void* d_ws, size_t ws_size,
                              hipStream_t stream) {
    const float* xyz1   = (const float*)d_in[0];
    const float* point1 = (const float*)d_in[1];
    const float* xyz2   = (const float*)d_in[2];
    const float* motion = (const float*)d_in[3];
    float* out = (float*)d_out;

    const int n1 = in_sizes[0] / 3;
    const int n2 = in_sizes[2] / 3;
    const int C  = in_sizes[1] / n1;
    const int nq = n2 * C;

    // ws layout (~13 MB): rbuck | qbuck | refspill | qspill | zero-zone
    char* ws = (char*)d_ws;
    size_t off = 0;
    auto alloc = [&](size_t bytes) {
        char* p = ws + off;
        off = (off + bytes + 255) & ~(size_t)255;
        return p;
    };
    float4* rbuck    = (float4*)alloc((size_t)NCELLS * CAPR * 16);
    float4* qbuck    = (float4*)alloc((size_t)NCELLS * CAPQ * 16);
    float4* refspill = (float4*)alloc((size_t)n1 * 16);
    float4* qspill   = (float4*)alloc((size_t)nq * 16);
    int*    zero     = (int*)alloc((size_t)(2 * NCELLS + 2) * 4);
    int* counts  = zero;
    int* qcounts = zero + NCELLS;
    int* rsn     = zero + 2 * NCELLS;
    int* qsn     = zero + 2 * NCELLS + 1;

    const int nmax = (n1 > nq) ? n1 : nq;

    hipMemsetAsync(zero, 0, (size_t)(2 * NCELLS + 2) * 4, stream);
    fused_scatter_kernel<<<(nmax + 255) / 256, 256, 0, stream>>>(
        xyz1, n1, xyz2, motion, n2, C,
        counts, qcounts, rbuck, qbuck, refspill, rsn, qspill, qsn);
    knn_cell_kernel<<<NCELLS, 128, 0, stream>>>(
        rbuck, counts, refspill, rsn, qbuck, qcounts, point1, out, C);
    qspill_kernel<<<1, 64, 0, stream>>>(
        qspill, qsn, rbuck, counts, refspill, rsn, point1, out, C);
}

// Round 15
// 169.378 us; speedup vs baseline: 30.0902x; 30.0902x over previous
//
#include <hip/hip_runtime.h>
#include <math.h>

#define KNN_EPS 1e-8f
// Spatial grid: domain [0,256)^3, cell h=16 -> 16^3 = 4096 cells.
#define GH 16.0f
#define GC 16
#define NCELLS (GC * GC * GC)
#define MARGIN 1.0f   // >> max |noisy_d - true_d| (~0.05) -> safe pruning
#define CAP 384       // staged candidates per block; 27-cell mean 132
#define CAPR 64       // ref bucket slots/cell (Poisson(4.9); P(>=64)~1e-40)
#define CAPQ 192      // query slots/cell. QUERIES CLUSTER 8-PER-BASE-POINT
                      // (C=8 share xyz2[n], motion ~N(0,1)) -> counts are
                      // ~8*Poisson(4.88); 192 = 8*24, P(Poisson>=24)*4096 ~ 1e-7.
                      // (r14's CAPQ=96 overflowed ~5 cells -> 5 ms spill path)

// ---------------------------------------------------------------------------
// Validated arithmetic (round 8, absmax 0.0547):
//   rsq/qsq: non-fused sequential squares; t: asc FMA chain;
//   d = max(fma(-2,t,fl(qsq+rsq)), 0); epilogue: +eps, IEEE div, seq sums.
// Selection: (d, idx) lexicographic min-3 -- order-independent, bit-identical
// across r10-r14 restructures (atomic bucket order is harmless).
// DO NOT change roundings -- only execution structure.
// ---------------------------------------------------------------------------

__device__ __forceinline__ int cell_coord(float v) {
    int c = (int)floorf(v * (1.0f / GH));
    return min(max(c, 0), GC - 1);
}

__global__ void fused_scatter_kernel(
    const float* __restrict__ xyz1, int n1,
    const float* __restrict__ xyz2,
    const float* __restrict__ motion, int n2, int C,
    int* __restrict__ counts, int* __restrict__ qcounts,
    float4* __restrict__ rbuck, float4* __restrict__ qbuck,
    float4* __restrict__ refspill, int* __restrict__ rsn,
    float4* __restrict__ qspill, int* __restrict__ qsn)
{
#pragma clang fp contract(off)
    int i = blockIdx.x * blockDim.x + threadIdx.x;
    if (i < n1) {
        float x = xyz1[3 * i + 0];
        float y = xyz1[3 * i + 1];
        float z = xyz1[3 * i + 2];
        int cid = (cell_coord(z) * GC + cell_coord(y)) * GC + cell_coord(x);
        int pos = atomicAdd(&counts[cid], 1);
        float4 v = make_float4(x, y, z, __int_as_float(i));
        if (pos < CAPR) rbuck[cid * CAPR + pos] = v;
        else { int sp = atomicAdd(rsn, 1); refspill[sp] = v; }
    }
    int nq = n2 * C;
    if (i < nq) {
        int n = i / C;
        float qx = xyz2[3 * n + 0] + motion[3 * i + 0];   // validated adds
        float qy = xyz2[3 * n + 1] + motion[3 * i + 1];
        float qz = xyz2[3 * n + 2] + motion[3 * i + 2];
        int cid = (cell_coord(qz) * GC + cell_coord(qy)) * GC + cell_coord(qx);
        int pos = atomicAdd(&qcounts[cid], 1);
        float4 v = make_float4(qx, qy, qz, __int_as_float(i));
        if (pos < CAPQ) qbuck[cid * CAPQ + pos] = v;
        else { int sp = atomicAdd(qsn, 1); qspill[sp] = v; }
    }
}

// (d, idx)-lexicographic insert: order-independent == validated stable scan.
__device__ __forceinline__ void top3_insert_lex(float d, int j,
                                                float& bd0, float& bd1, float& bd2,
                                                int& bi0, int& bi1, int& bi2) {
    if (d < bd2 || (d == bd2 && j < bi2)) {
        if (d < bd1 || (d == bd1 && j < bi1)) {
            bd2 = bd1; bi2 = bi1;
            if (d < bd0 || (d == bd0 && j < bi0)) {
                bd1 = bd0; bi1 = bi0;
                bd0 = d;   bi0 = j;
            } else {
                bd1 = d;   bi1 = j;
            }
        } else {
            bd2 = d;       bi2 = j;
        }
    }
}

// Validated candidate evaluation (round 8 roundings, rsq recomputed bit-equal)
__device__ __forceinline__ void eval_candidate(
    float4 r, float qx, float qy, float qz, float qsq,
    float& bd0, float& bd1, float& bd2, int& bi0, int& bi1, int& bi2) {
    int ridx = __float_as_int(r.w);
    float rsq = r.x * r.x + r.y * r.y;
    rsq = rsq + r.z * r.z;
    float t = fmaf(qz, r.z, fmaf(qy, r.y, qx * r.x));
    float h = qsq + rsq;
    float d = fmaxf(fmaf(-2.0f, t, h), 0.0f);
    top3_insert_lex(d, ridx, bd0, bd1, bd2, bi0, bi1, bi2);
}

// Rigorous certification radius after scanning cell-rings <= rho.
__device__ __forceinline__ float cert_radius(float qx, float qy, float qz,
                                             int icx, int icy, int icz, int rho) {
    float R = INFINITY;
    if (icx - rho > 0)      R = fminf(R, qx - (float)(icx - rho) * GH);
    if (icx + rho < GC - 1) R = fminf(R, (float)(icx + rho + 1) * GH - qx);
    if (icy - rho > 0)      R = fminf(R, qy - (float)(icy - rho) * GH);
    if (icy + rho < GC - 1) R = fminf(R, (float)(icy + rho + 1) * GH - qy);
    if (icz - rho > 0)      R = fminf(R, qz - (float)(icz - rho) * GH);
    if (icz + rho < GC - 1) R = fminf(R, (float)(icz + rho + 1) * GH - qz);
    return R;
}

// Validated epilogue (round 8) -> writes out[qid]
__device__ __forceinline__ void epilogue_store(
    float bd0, float bd1, float bd2, int bi0, int bi1, int bi2,
    int qid, int C, const float* __restrict__ point1, float* __restrict__ out) {
#pragma clang fp contract(off)
    float dd0 = bd0 + KNN_EPS;
    float dd1 = bd1 + KNN_EPS;
    float dd2 = bd2 + KNN_EPS;
    float w0 = 1.0f / dd0;
    float w1 = 1.0f / dd1;
    float w2 = 1.0f / dd2;
    float s  = w0 + w1;
    s = s + w2;
    float m = fmaxf(s, 3.0f);
    w0 = w0 / m;
    w1 = w1 / m;
    w2 = w2 / m;
    const int c = qid - (qid / C) * C;
    float p0 = point1[bi0 * C + c];
    float p1 = point1[bi1 * C + c];
    float p2 = point1[bi2 * C + c];
    float acc = w0 * p0 + w1 * p1;
    acc = acc + w2 * p2;
    out[qid] = acc;
}

// Full ring search for ONE query over the bucket structure (+ref spill).
// Order-independent selection -> bit-identical to any other scan order.
__device__ void ring_search(float qx, float qy, float qz, float qsq,
                            const float4* __restrict__ rbuck,
                            const int* __restrict__ counts, int rspn,
                            const float4* __restrict__ refspill,
                            float& bd0, float& bd1, float& bd2,
                            int& bi0, int& bi1, int& bi2) {
    const int icx = cell_coord(qx);
    const int icy = cell_coord(qy);
    const int icz = cell_coord(qz);
    for (int k = 0; k < rspn; ++k)
        eval_candidate(refspill[k], qx, qy, qz, qsq, bd0, bd1, bd2, bi0, bi1, bi2);
    for (int rho = 0; rho < GC; ++rho) {
        for (int dz = -rho; dz <= rho; ++dz) {
            int cz = icz + dz;
            if (cz < 0 || cz >= GC) continue;
            int adz = (dz < 0) ? -dz : dz;
            for (int dy = -rho; dy <= rho; ++dy) {
                int cy = icy + dy;
                if (cy < 0 || cy >= GC) continue;
                int ady = (dy < 0) ? -dy : dy;
                int step = (adz == rho || ady == rho || rho == 0) ? 1 : 2 * rho;
                for (int dx = -rho; dx <= rho; dx += step) {
                    int cx = icx + dx;
                    if (cx < 0 || cx >= GC) continue;
                    int cid = (cz * GC + cy) * GC + cx;
                    int e = min(counts[cid], CAPR);
                    for (int s = 0; s < e; ++s)
                        eval_candidate(rbuck[cid * CAPR + s], qx, qy, qz, qsq,
                                       bd0, bd1, bd2, bi0, bi1, bi2);
                }
            }
        }
        float Rr = cert_radius(qx, qy, qz, icx, icy, icz, rho);
        if (bd2 + MARGIN <= Rr * Rr) break;  // Rr=INF also breaks
    }
}

// One block (2 waves) per cell (r13/r14 structure, bit-exact validated).
__global__ __launch_bounds__(128, 8) void knn_cell_kernel(
    const float4* __restrict__ rbuck,
    const int*   __restrict__ counts,
    const float4* __restrict__ refspill,
    const int*   __restrict__ rsn,
    const float4* __restrict__ qbuck,
    const int*   __restrict__ qcounts,
    const float* __restrict__ point1,
    float* __restrict__ out,
    int C)
{
#pragma clang fp contract(off)
    const int cell = blockIdx.x;
    const int qn = min(qcounts[cell], CAPQ);
    if (qn == 0) return;
    const int qbase = cell * CAPQ;

    const int tid = threadIdx.x;
    const int lane = tid & 63;
    const int wave = tid >> 6;

    const int icx = cell & (GC - 1);
    const int icy = (cell >> 4) & (GC - 1);
    const int icz = cell >> 8;

    __shared__ float4 cand[CAP];
    __shared__ int rcid[27], rlen[27], rofs[27], rst[27];
    __shared__ int total_s, ovf_s, rsn_s;
    __shared__ float pbd[64][3];
    __shared__ int   pbi[64][3];

    if (tid < 27) {
        int dz = tid / 9 - 1, dy = (tid / 3) % 3 - 1, dx = tid % 3 - 1;
        int cz = icz + dz, cy = icy + dy, cx = icx + dx;
        int ok = (cz >= 0 && cz < GC && cy >= 0 && cy < GC && cx >= 0 && cx < GC);
        int cid = ok ? (cz * GC + cy) * GC + cx : 0;
        rcid[tid] = cid;
        rlen[tid] = ok ? min(counts[cid], CAPR) : 0;
    }
    if (tid == 32) rsn_s = *rsn;
    __syncthreads();
    if (tid == 0) {   // pure-VALU 27-element prefix on LDS-resident ints
        int run = 0, ovf = 0;
        for (int r = 0; r < 27; ++r) {
            int len = rlen[r];
            int st = min(len, CAP - run);
            rofs[r] = run; rst[r] = st;
            run += st;
            if (st < len) ovf = 1;
        }
        total_s = run; ovf_s = ovf;
    }
    __syncthreads();

    const int total = total_s;
    const int ovf = ovf_s;
    const int rspn = rsn_s;

    for (int i = tid; i < total; i += 128) {
        int lo = 0, hi = 26;
        while (lo < hi) {
            int mid = (lo + hi + 1) >> 1;
            if (rofs[mid] <= i) lo = mid; else hi = mid - 1;
        }
        cand[i] = rbuck[rcid[lo] * CAPR + (i - rofs[lo])];
    }
    __syncthreads();

    const int half = total >> 1;
    const int k0 = wave ? half : 0;
    const int k1 = wave ? total : half;

    const int niter = (qn + 63) >> 6;
    for (int it = 0; it < niter; ++it) {
        const int qo = it * 64 + lane;
        const bool active = qo < qn;
        float4 Q = qbuck[qbase + (active ? qo : 0)];
        const float qx = Q.x, qy = Q.y, qz = Q.z;
        const int qid = __float_as_int(Q.w);
        float qsq = qx * qx + qy * qy;
        qsq = qsq + qz * qz;

        float bd0 = INFINITY, bd1 = INFINITY, bd2 = INFINITY;
        int   bi0 = 0,        bi1 = 0,        bi2 = 0;

        int k = k0;
        for (; k + 4 <= k1; k += 4) {
            float4 c0 = cand[k + 0];
            float4 c1 = cand[k + 1];
            float4 c2 = cand[k + 2];
            float4 c3 = cand[k + 3];
            eval_candidate(c0, qx, qy, qz, qsq, bd0, bd1, bd2, bi0, bi1, bi2);
            eval_candidate(c1, qx, qy, qz, qsq, bd0, bd1, bd2, bi0, bi1, bi2);
            eval_candidate(c2, qx, qy, qz, qsq, bd0, bd1, bd2, bi0, bi1, bi2);
            eval_candidate(c3, qx, qy, qz, qsq, bd0, bd1, bd2, bi0, bi1, bi2);
        }
        for (; k < k1; ++k)
            eval_candidate(cand[k], qx, qy, qz, qsq, bd0, bd1, bd2, bi0, bi1, bi2);

        if (wave == 1) {
            pbd[lane][0] = bd0; pbd[lane][1] = bd1; pbd[lane][2] = bd2;
            pbi[lane][0] = bi0; pbi[lane][1] = bi1; pbi[lane][2] = bi2;
        }
        __syncthreads();

        if (wave == 0) {
            for (int m = 0; m < 3; ++m) {
                float d = pbd[lane][m];
                if (d < INFINITY)
                    top3_insert_lex(d, pbi[lane][m], bd0, bd1, bd2, bi0, bi1, bi2);
            }
            for (int k2 = 0; k2 < rspn; ++k2)
                eval_candidate(refspill[k2], qx, qy, qz, qsq,
                               bd0, bd1, bd2, bi0, bi1, bi2);
            if (ovf) {
                for (int r = 0; r < 27; ++r)
                    for (int kk = rst[r]; kk < rlen[r]; ++kk)
                        eval_candidate(rbuck[rcid[r] * CAPR + kk], qx, qy, qz, qsq,
                                       bd0, bd1, bd2, bi0, bi1, bi2);
            }
            float R = cert_radius(qx, qy, qz, icx, icy, icz, 1);
            if (!(bd2 + MARGIN <= R * R)) {
                for (int rho = 2; rho < GC; ++rho) {
                    for (int dz = -rho; dz <= rho; ++dz) {
                        int cz = icz + dz;
                        if (cz < 0 || cz >= GC) continue;
                        int adz = (dz < 0) ? -dz : dz;
                        for (int dy = -rho; dy <= rho; ++dy) {
                            int cy = icy + dy;
                            if (cy < 0 || cy >= GC) continue;
                            int ady = (dy < 0) ? -dy : dy;
                            int step = (adz == rho || ady == rho) ? 1 : 2 * rho;
                            for (int dx = -rho; dx <= rho; dx += step) {
                                int cx = icx + dx;
                                if (cx < 0 || cx >= GC) continue;
                                int cid = (cz * GC + cy) * GC + cx;
                                int e = min(counts[cid], CAPR);
                                for (int s = 0; s < e; ++s)
                                    eval_candidate(rbuck[cid * CAPR + s],
                                                   qx, qy, qz, qsq,
                                                   bd0, bd1, bd2, bi0, bi1, bi2);
                            }
                        }
                    }
                    float Rr = cert_radius(qx, qy, qz, icx, icy, icz, rho);
                    if (bd2 + MARGIN <= Rr * Rr) break;
                }
            }

            if (active)
                epilogue_store(bd0, bd1, bd2, bi0, bi1, bi2, qid, C, point1, out);
        }
        if (it + 1 < niter) __syncthreads();
    }
}

// Spilled queries: PARALLEL (grid-strided) ring search -- costs microseconds
// even if taken (r14's serial exhaustive version cost 5 ms when CAPQ
// overflowed; CAPQ=192 makes overflow ~1e-7 but this stays cheap regardless).
__global__ __launch_bounds__(256) void qspill_kernel(
    const float4* __restrict__ qspill, const int* __restrict__ qsn,
    const float4* __restrict__ rbuck, const int* __restrict__ counts,
    const float4* __restrict__ refspill, const int* __restrict__ rsn,
    const float* __restrict__ point1, float* __restrict__ out, int C)
{
#pragma clang fp contract(off)
    const int nsp = *qsn;
    const int rspn = *rsn;
    for (int s = blockIdx.x * blockDim.x + threadIdx.x; s < nsp;
         s += gridDim.x * blockDim.x) {
        float4 Q = qspill[s];
        const float qx = Q.x, qy = Q.y, qz = Q.z;
        const int qid = __float_as_int(Q.w);
        float qsq = qx * qx + qy * qy;
        qsq = qsq + qz * qz;
        float bd0 = INFINITY, bd1 = INFINITY, bd2 = INFINITY;
        int   bi0 = 0,        bi1 = 0,        bi2 = 0;
        ring_search(qx, qy, qz, qsq, rbuck, counts, rspn, refspill,
                    bd0, bd1, bd2, bi0, bi1, bi2);
        epilogue_store(bd0, bd1, bd2, bi0, bi1, bi2, qid, C, point1, out);
    }
}

extern "C" void kernel_launch(void* const* d_in, const int* in_sizes, int n_in,
                              void* d_out, int out_size, void* d_ws, size_t ws_size,
                              hipStream_t stream) {
    const float* xyz1   = (const float*)d_in[0];
    const float* point1 = (const float*)d_in[1];
    const float* xyz2   = (const float*)d_in[2];
    const float* motion = (const float*)d_in[3];
    float* out = (float*)d_out;

    const int n1 = in_sizes[0] / 3;
    const int n2 = in_sizes[2] / 3;
    const int C  = in_sizes[1] / n1;
    const int nq = n2 * C;

    // ws layout (~20 MB): rbuck | qbuck | refspill | qspill | zero-zone
    char* ws = (char*)d_ws;
    size_t off = 0;
    auto alloc = [&](size_t bytes) {
        char* p = ws + off;
        off = (off + bytes + 255) & ~(size_t)255;
        return p;
    };
    float4* rbuck    = (float4*)alloc((size_t)NCELLS * CAPR * 16);
    float4* qbuck    = (float4*)alloc((size_t)NCELLS * CAPQ * 16);
    float4* refspill = (float4*)alloc((size_t)n1 * 16);
    float4* qspill   = (float4*)alloc((size_t)nq * 16);
    int*    zero     = (int*)alloc((size_t)(2 * NCELLS + 2) * 4);
    int* counts  = zero;
    int* qcounts = zero + NCELLS;
    int* rsn     = zero + 2 * NCELLS;
    int* qsn     = zero + 2 * NCELLS + 1;

    const int nmax = (n1 > nq) ? n1 : nq;

    hipMemsetAsync(zero, 0, (size_t)(2 * NCELLS + 2) * 4, stream);
    fused_scatter_kernel<<<(nmax + 255) / 256, 256, 0, stream>>>(
        xyz1, n1, xyz2, motion, n2, C,
        counts, qcounts, rbuck, qbuck, refspill, rsn, qspill, qsn);
    knn_cell_kernel<<<NCELLS, 128, 0, stream>>>(
        rbuck, counts, refspill, rsn, qbuck, qcounts, point1, out, C);
    qspill_kernel<<<4, 256, 0, stream>>>(
        qspill, qsn, rbuck, counts, refspill, rsn, point1, out, C);
}